// Round 3
// baseline (795.318 us; speedup 1.0000x reference)
//
#include <hip/hip_runtime.h>

// Problem constants
#define BB 4
#define TT 2048
#define CC 2048
#define NHEAD 16
#define DH 128
#define MM (BB * TT)          // 8192 rows
#define N3 (3 * CC)           // 6144
#define LD3 6144

typedef unsigned short u16;
typedef __attribute__((ext_vector_type(8))) short short8;
typedef __attribute__((ext_vector_type(4))) float f32x4;

__device__ __forceinline__ u16 f2bf(float f) {
  unsigned u = __float_as_uint(f);
  u += 0x7fffu + ((u >> 16) & 1u);      // RNE
  return (u16)(u >> 16);
}
__device__ __forceinline__ float bf2f(u16 h) {
  return __uint_as_float(((unsigned)h) << 16);
}

__device__ __forceinline__ void gload_lds16(const void* g, void* l) {
  __builtin_amdgcn_global_load_lds((const __attribute__((address_space(1))) void*)g,
                                   (__attribute__((address_space(3))) void*)l, 16, 0, 0);
}

__device__ __forceinline__ f32x4 mfma16(short8 a, short8 b, f32x4 c) {
  return __builtin_amdgcn_mfma_f32_16x16x32_bf16(a, b, c, 0, 0, 0);
}

// ---------------------------------------------------------------- convert x
__global__ void convert_x_kernel(const float* __restrict__ x, u16* __restrict__ xb) {
  const int total = (MM * CC) / 4;
  const float4* xv = (const float4*)x;
  ushort4* ov = (ushort4*)xb;
  for (int i = blockIdx.x * blockDim.x + threadIdx.x; i < total; i += gridDim.x * blockDim.x) {
    float4 v = xv[i];
    ushort4 o;
    o.x = f2bf(v.x); o.y = f2bf(v.y); o.z = f2bf(v.z); o.w = f2bf(v.w);
    ov[i] = o;
  }
}

// ------------------------------------------- transpose + convert W -> W^T bf16
__global__ void transpose_bf16_kernel(const float* __restrict__ W, u16* __restrict__ Wt,
                                      int rows, int cols) {
  __shared__ float tile[32][33];
  const int n0 = blockIdx.x * 32, k0 = blockIdx.y * 32;
  const int tx = threadIdx.x, ty = threadIdx.y;   // (32, 8)
  #pragma unroll
  for (int i = 0; i < 4; ++i)
    tile[ty + 8 * i][tx] = W[(size_t)(k0 + ty + 8 * i) * cols + n0 + tx];
  __syncthreads();
  #pragma unroll
  for (int i = 0; i < 4; ++i)
    Wt[(size_t)(n0 + ty + 8 * i) * rows + k0 + tx] = f2bf(tile[tx][ty + 8 * i]);
}

// ---------------------------------------------------------------- rope table
__global__ void rope_table_kernel(float2* __restrict__ tab) {
  int idx = blockIdx.x * 256 + threadIdx.x;     // T*64 entries
  int t = idx >> 6, f = idx & 63;
  float freq = expf(-0.14391156831f * (float)f);   // 10000^(-f/64)
  float ang = (float)t * freq;
  float s, c;
  sincosf(ang, &s, &c);
  tab[idx] = make_float2(c, s);
}

// ------------------------------------------------------- rope apply (q and k)
__global__ void rope_apply_kernel(u16* __restrict__ qkv, const float2* __restrict__ tab) {
  int idx = blockIdx.x * 256 + threadIdx.x;   // 2^24 = 2 * M * 16 * 64
  int f = idx & 63;
  int h = (idx >> 6) & 15;
  int m = (idx >> 10) & 8191;
  int which = idx >> 23;                      // 0 = q, 1 = k
  int t = m & (TT - 1);
  u16* p = qkv + (size_t)m * LD3 + which * CC + h * DH + f;
  float2 cs = tab[(t << 6) + f];
  float x1 = bf2f(p[0]), x2 = bf2f(p[64]);
  float o1 = x1 * cs.x - x2 * cs.y;
  float o2 = x2 * cs.x + x1 * cs.y;
  if (which == 0) { o1 *= 0.08838834764831845f; o2 *= 0.08838834764831845f; }
  p[0] = f2bf(o1);
  p[64] = f2bf(o2);
}

// ------------------------------------------------------------------- GEMM
// C[m][n] = sum_k A[m][k] * Bt[n][k];  A: M x K bf16, Bt: N x K bf16.
// 128x128 tile, 4 waves, BK=32, global_load_lds staging (m97 structure).
__global__ __launch_bounds__(256) void gemm_bt_128(const u16* __restrict__ A,
                                                   const u16* __restrict__ Bt,
                                                   void* __restrict__ Cout,
                                                   int K, int ldc, int out_bf16) {
  __shared__ __align__(16) u16 As[128 * 32];
  __shared__ __align__(16) u16 Bs[128 * 32];
  const int tid = threadIdx.x;
  const int wid = tid >> 6, lane = tid & 63;
  const int l15 = lane & 15, g = lane >> 4;
  const int row0 = blockIdx.y * 128, col0 = blockIdx.x * 128;
  const int wr = (wid >> 1) * 64, wc = (wid & 1) * 64;
  f32x4 acc[4][4];
  #pragma unroll
  for (int m = 0; m < 4; ++m)
    #pragma unroll
    for (int n = 0; n < 4; ++n)
      acc[m][n] = (f32x4){0.f, 0.f, 0.f, 0.f};

  for (int k0 = 0; k0 < K; k0 += 32) {
    #pragma unroll
    for (int c = 0; c < 2; ++c) {
      int chunk = c * 256 + tid;          // 0..511 ; 8-bf16 chunks of the 128x32 tile
      int r = chunk >> 2, co = chunk & 3;
      gload_lds16(A + (size_t)(row0 + r) * K + k0 + co * 8, &As[(c * 256 + wid * 64) * 8]);
      gload_lds16(Bt + (size_t)(col0 + r) * K + k0 + co * 8, &Bs[(c * 256 + wid * 64) * 8]);
    }
    asm volatile("s_waitcnt vmcnt(0)" ::: "memory");
    __syncthreads();
    short8 af[4], bfr[4];
    #pragma unroll
    for (int m = 0; m < 4; ++m)
      af[m] = *(const short8*)&As[(wr + m * 16 + l15) * 32 + g * 8];
    #pragma unroll
    for (int n = 0; n < 4; ++n)
      bfr[n] = *(const short8*)&Bs[(wc + n * 16 + l15) * 32 + g * 8];
    #pragma unroll
    for (int m = 0; m < 4; ++m)
      #pragma unroll
      for (int n = 0; n < 4; ++n)
        acc[m][n] = mfma16(af[m], bfr[n], acc[m][n]);
    __syncthreads();
  }

  if (out_bf16) {
    u16* Cb = (u16*)Cout;
    #pragma unroll
    for (int m = 0; m < 4; ++m)
      #pragma unroll
      for (int n = 0; n < 4; ++n) {
        int row = row0 + wr + m * 16 + 4 * g;
        int col = col0 + wc + n * 16 + l15;
        #pragma unroll
        for (int j = 0; j < 4; ++j)
          Cb[(size_t)(row + j) * ldc + col] = f2bf(acc[m][n][j]);
      }
  } else {
    float* Cf = (float*)Cout;
    #pragma unroll
    for (int m = 0; m < 4; ++m)
      #pragma unroll
      for (int n = 0; n < 4; ++n) {
        int row = row0 + wr + m * 16 + 4 * g;
        int col = col0 + wc + n * 16 + l15;
        #pragma unroll
        for (int j = 0; j < 4; ++j)
          Cf[(size_t)(row + j) * ldc + col] = acc[m][n][j];
      }
  }
}

// ---------------------------------------------------------------- attention
// Double-buffered K/V tiles + pipelined staging (stage tile it+1 while
// computing tile it). An LDS buffer is never written while any wave can
// still be reading it (reuse distance = 2 iterations, 2 barriers).
#define QBLK 64
#define KBLK 64
#define PADV 72
#define PADP 72

__global__ __launch_bounds__(256) void attn_kernel(const u16* __restrict__ qkv,
                                                   u16* __restrict__ y) {
  __shared__ __align__(16) u16 Ks[2][KBLK * 128];   // swizzled K tiles; Ks[1] holds Q first
  __shared__ __align__(16) u16 Vt[2][DH * PADV];    // V transposed [d][kv], padded
  __shared__ __align__(16) u16 Pl[4 * 16 * PADP];   // per-wave P round-trip
  const int tid = threadIdx.x;
  const int wid = tid >> 6, lane = tid & 63;
  const int l15 = lane & 15, g = lane >> 4;
  const int qt0 = blockIdx.x * QBLK;
  const int b = blockIdx.y >> 4, h = blockIdx.y & 15;
  const size_t rb = (size_t)b * TT;
  const int vk0 = (tid & 15) * 4, vd0 = (tid >> 4) * 8;   // V-staging assignment

  // ---- prologue: stage Q -> Ks[1], K(tile0) -> Ks[0], V(tile0) -> Vt[0]
  {
    const u16* qbase = qkv + (rb + qt0) * LD3 + h * DH;
    const u16* kbase = qkv + rb * LD3 + CC + h * DH;
    #pragma unroll
    for (int c = 0; c < 4; ++c) {
      int chunk = c * 256 + tid;
      int r = chunk >> 4, s = chunk & 15;
      gload_lds16(qbase + (size_t)r * LD3 + (size_t)((s ^ (r & 7)) * 8),
                  &Ks[1][(c * 256 + wid * 64) * 8]);
      gload_lds16(kbase + (size_t)r * LD3 + (size_t)((s ^ (r & 7)) * 8),
                  &Ks[0][(c * 256 + wid * 64) * 8]);
    }
    const u16* vg = qkv + (rb + vk0) * LD3 + 2 * CC + h * DH + vd0;
    short8 r0 = *(const short8*)vg;
    short8 r1 = *(const short8*)(vg + LD3);
    short8 r2 = *(const short8*)(vg + 2 * LD3);
    short8 r3 = *(const short8*)(vg + 3 * LD3);
    #pragma unroll
    for (int j = 0; j < 8; ++j) {
      ushort4 w;
      w.x = (u16)r0[j]; w.y = (u16)r1[j]; w.z = (u16)r2[j]; w.w = (u16)r3[j];
      *(ushort4*)&Vt[0][(vd0 + j) * PADV + vk0] = w;
    }
  }
  asm volatile("s_waitcnt vmcnt(0)" ::: "memory");
  __syncthreads();

  // ---- load Q fragments from Ks[1]
  short8 qf[4];
  #pragma unroll
  for (int kk = 0; kk < 4; ++kk) {
    int row = wid * 16 + l15;
    qf[kk] = *(const short8*)((const char*)Ks[1] + row * 256 +
                              ((kk * 64 + g * 16) ^ ((l15 & 7) << 4)));
  }
  __syncthreads();   // all waves' qf reads drained before Ks[1] is re-staged

  f32x4 o[8];
  #pragma unroll
  for (int nf = 0; nf < 8; ++nf) o[nf] = (f32x4){0.f, 0.f, 0.f, 0.f};
  float mrun[4] = {-1e30f, -1e30f, -1e30f, -1e30f};
  float lrun[4] = {0.f, 0.f, 0.f, 0.f};

  const int nt = qt0 / KBLK + 1;
  for (int it = 0; it < nt; ++it) {
    const int cur = it & 1, nxt = cur ^ 1;
    const bool havenext = (it + 1) < nt;
    short8 r0, r1, r2, r3;
    if (havenext) {
      const int kvn = (it + 1) * KBLK;
      // issue K staging (fire-and-forget DMA into the other buffer)
      const u16* kbase = qkv + (rb + kvn) * LD3 + CC + h * DH;
      #pragma unroll
      for (int c = 0; c < 4; ++c) {
        int chunk = c * 256 + tid;
        int r = chunk >> 4, s = chunk & 15;
        gload_lds16(kbase + (size_t)r * LD3 + (size_t)((s ^ (r & 7)) * 8),
                    &Ks[nxt][(c * 256 + wid * 64) * 8]);
      }
      // issue V global loads now; ds_write them after compute (T14 split)
      const u16* vg = qkv + (rb + kvn + vk0) * LD3 + 2 * CC + h * DH + vd0;
      r0 = *(const short8*)vg;
      r1 = *(const short8*)(vg + LD3);
      r2 = *(const short8*)(vg + 2 * LD3);
      r3 = *(const short8*)(vg + 3 * LD3);
    }

    // ---- S = Q K^T from Ks[cur] (q pre-scaled by 1/sqrt(D))
    f32x4 s4[4];
    #pragma unroll
    for (int jf = 0; jf < 4; ++jf) s4[jf] = (f32x4){0.f, 0.f, 0.f, 0.f};
    #pragma unroll
    for (int jf = 0; jf < 4; ++jf) {
      int row = jf * 16 + l15;
      #pragma unroll
      for (int kk = 0; kk < 4; ++kk) {
        short8 kf = *(const short8*)((const char*)Ks[cur] + row * 256 +
                                     ((kk * 64 + g * 16) ^ ((l15 & 7) << 4)));
        s4[jf] = mfma16(qf[kk], kf, s4[jf]);
      }
    }
    // causal mask: only the diagonal (last) tile
    if (it == nt - 1) {
      #pragma unroll
      for (int jf = 0; jf < 4; ++jf)
        #pragma unroll
        for (int j = 0; j < 4; ++j)
          if (jf * 16 + l15 > wid * 16 + 4 * g + j) s4[jf][j] = -1e30f;
    }
    // ---- online softmax (rows live across g-groups' 16 lanes)
    float rmax[4], corr[4], rsum[4];
    #pragma unroll
    for (int j = 0; j < 4; ++j)
      rmax[j] = fmaxf(fmaxf(s4[0][j], s4[1][j]), fmaxf(s4[2][j], s4[3][j]));
    #pragma unroll
    for (int j = 0; j < 4; ++j) {
      rmax[j] = fmaxf(rmax[j], __shfl_xor(rmax[j], 1, 64));
      rmax[j] = fmaxf(rmax[j], __shfl_xor(rmax[j], 2, 64));
      rmax[j] = fmaxf(rmax[j], __shfl_xor(rmax[j], 4, 64));
      rmax[j] = fmaxf(rmax[j], __shfl_xor(rmax[j], 8, 64));
    }
    #pragma unroll
    for (int j = 0; j < 4; ++j) {
      float mn = fmaxf(mrun[j], rmax[j]);
      corr[j] = __expf(mrun[j] - mn);
      mrun[j] = mn;
    }
    #pragma unroll
    for (int jf = 0; jf < 4; ++jf)
      #pragma unroll
      for (int j = 0; j < 4; ++j)
        s4[jf][j] = __expf(s4[jf][j] - mrun[j]);
    #pragma unroll
    for (int j = 0; j < 4; ++j) {
      rsum[j] = (s4[0][j] + s4[1][j]) + (s4[2][j] + s4[3][j]);
      rsum[j] += __shfl_xor(rsum[j], 1, 64);
      rsum[j] += __shfl_xor(rsum[j], 2, 64);
      rsum[j] += __shfl_xor(rsum[j], 4, 64);
      rsum[j] += __shfl_xor(rsum[j], 8, 64);
      lrun[j] = lrun[j] * corr[j] + rsum[j];
    }
    #pragma unroll
    for (int nf = 0; nf < 8; ++nf)
      #pragma unroll
      for (int j = 0; j < 4; ++j)
        o[nf][j] *= corr[j];

    // ---- P: D-layout -> A-layout via per-wave LDS round-trip (bf16)
    u16* Pw = &Pl[wid * 16 * PADP];
    #pragma unroll
    for (int jf = 0; jf < 4; ++jf)
      #pragma unroll
      for (int j = 0; j < 4; ++j)
        Pw[(4 * g + j) * PADP + jf * 16 + l15] = f2bf(s4[jf][j]);
    // fence the same-wave write->read round-trip (rule #18 hardening)
    asm volatile("s_waitcnt lgkmcnt(0)" ::: "memory");
    __builtin_amdgcn_sched_barrier(0);
    short8 pf[2];
    #pragma unroll
    for (int kk = 0; kk < 2; ++kk)
      pf[kk] = *(const short8*)&Pw[l15 * PADP + kk * 32 + g * 8];

    // ---- O += P V from Vt[cur]
    #pragma unroll
    for (int nf = 0; nf < 8; ++nf) {
      #pragma unroll
      for (int kk = 0; kk < 2; ++kk) {
        short8 vf = *(const short8*)&Vt[cur][(nf * 16 + l15) * PADV + kk * 32 + g * 8];
        o[nf] = mfma16(pf[kk], vf, o[nf]);
      }
    }

    // ---- late V write into the other buffer (global-load latency hidden)
    if (havenext) {
      #pragma unroll
      for (int j = 0; j < 8; ++j) {
        ushort4 w;
        w.x = (u16)r0[j]; w.y = (u16)r1[j]; w.z = (u16)r2[j]; w.w = (u16)r3[j];
        *(ushort4*)&Vt[nxt][(vd0 + j) * PADV + vk0] = w;
      }
    }
    asm volatile("s_waitcnt vmcnt(0)" ::: "memory");
    __syncthreads();
  }

  float inv[4];
  #pragma unroll
  for (int j = 0; j < 4; ++j) inv[j] = 1.0f / lrun[j];
  #pragma unroll
  for (int nf = 0; nf < 8; ++nf)
    #pragma unroll
    for (int j = 0; j < 4; ++j)
      y[(rb + qt0 + wid * 16 + 4 * g + j) * CC + h * DH + nf * 16 + l15] =
          f2bf(o[nf][j] * inv[j]);
}

// ------------------------------------------------------------------ launch
// Workspace layout: R1's exact non-aliased layout (the only config that has
// passed validation-1). 193 MB total, no time-sharing.
extern "C" void kernel_launch(void* const* d_in, const int* in_sizes, int n_in,
                              void* d_out, int out_size, void* d_ws, size_t ws_size,
                              hipStream_t stream) {
  const float* x = (const float*)d_in[0];
  const float* Wqkv = (const float*)d_in[1];
  const float* Wproj = (const float*)d_in[2];
  char* ws = (char*)d_ws;
  u16* xb     = (u16*)(ws);                      // 32 MB
  u16* wqkvT  = (u16*)(ws + 33554432);           // 24 MB
  u16* wprojT = (u16*)(ws + 58720256);           // 8 MB
  u16* qkv    = (u16*)(ws + 67108864);           // 96 MB
  u16* y      = (u16*)(ws + 167772160);          // 32 MB
  float2* tab = (float2*)(ws + 201326592);       // 1 MB

  convert_x_kernel<<<4096, 256, 0, stream>>>(x, xb);
  transpose_bf16_kernel<<<dim3(192, 64), dim3(32, 8), 0, stream>>>(Wqkv, wqkvT, CC, N3);
  transpose_bf16_kernel<<<dim3(64, 64), dim3(32, 8), 0, stream>>>(Wproj, wprojT, CC, CC);
  rope_table_kernel<<<512, 256, 0, stream>>>(tab);
  gemm_bt_128<<<dim3(48, 64), 256, 0, stream>>>(xb, wqkvT, (void*)qkv, CC, LD3, 1);
  rope_apply_kernel<<<65536, 256, 0, stream>>>(qkv, tab);
  attn_kernel<<<dim3(32, 64), 256, 0, stream>>>(qkv, y);
  gemm_bt_128<<<dim3(16, 64), 256, 0, stream>>>(y, wprojT, d_out, CC, CC, 0);
}